// Round 9
// baseline (469.744 us; speedup 1.0000x reference)
//
#include <hip/hip_runtime.h>
#include <stdint.h>

#define NEURONS 512
#define SYN     784
#define TIN     500
#define TP      522
#define TPAD    528
#define BATCH   64
#define NCOL    (BATCH*TPAD)   // 33792
#define XW2     18             // xbT words per (b,*,s): word0 guard, 1..16 data, 17 guard
#define NKK     98             // K iterations (6272 / 64)

typedef int i32x4 __attribute__((ext_vector_type(4)));

// ---------------------------------------------------------------- A pack
// One-hot int8 weights, MFMA-fragment-packed (verified R3/R4):
// uint2 slot u <-> (kk, rowblk, quad, m=l15, half): byte k = s*8+w mapping.
__global__ void k_apack(const int* __restrict__ w, uint2* __restrict__ apk) {
    int u = blockIdx.x * 256 + threadIdx.x;            // 401408 slots
    int half = u & 1, m = (u >> 1) & 15, quad = (u >> 5) & 3;
    int rowblk = (u >> 7) & 31, kk = u >> 12;
    int n = rowblk * 16 + m;
    int s = kk * 8 + quad * 2 + half;
    int wv = w[n * SYN + s];
    uint2 v;
    v.x = (wv < 4)  ? (1u << (8 * wv))       : 0u;
    v.y = (wv >= 4) ? (1u << (8 * (wv - 4))) : 0u;
    apk[u] = v;
}

// ---------------------------------------------------------------- spike bits, transposed
// xbT[(b*18 + word)*784 + s]; word 0,17 guards; word w in 1..16: bit j = spike at
// tau=(w-1)*32+j. Coalesced: LDS nibble transpose, 16 rows per 256-thr block.
__global__ void k_xbitsT(const float* __restrict__ x, uint32_t* __restrict__ xbT) {
    __shared__ unsigned char nib[16][128];
    int tid = threadIdx.x;
    int r0  = blockIdx.x * 16;                         // 3136 blocks, 784%16==0 -> b uniform
    for (int e = tid; e < 2048; e += 256) {
        int row = e >> 7, q4 = e & 127;
        unsigned char v = 0;
        if (q4 < 125) {
            float4 f = *(const float4*)(x + (size_t)(r0 + row) * TIN + q4 * 4);
            v = (unsigned char)((f.x != 0.f) | ((f.y != 0.f) << 1) |
                                ((f.z != 0.f) << 2) | ((f.w != 0.f) << 3));
        }
        nib[row][q4] = v;
    }
    __syncthreads();
    int row = tid >> 4, d = tid & 15;
    uint64_t u = *(const uint64_t*)&nib[row][d * 8];
    uint32_t wd = 0;
#pragma unroll
    for (int q = 0; q < 8; ++q)
        wd |= ((uint32_t)((u >> (8 * q)) & 0xFull)) << (4 * q);
    if (d == 15) wd &= 0xFFFFFu;                       // taus 480..499 only
    int grow = r0 + row;
    int b = grow / SYN, s = grow - b * SYN;
    xbT[(size_t)(b * XW2 + 1 + d) * SYN + s] = wd;
    if (d == 0) {
        xbT[(size_t)(b * XW2) * SYN + s] = 0u;         // guard word 0
        xbT[(size_t)(b * XW2 + 17) * SYN + s] = 0u;    // guard word 17
    }
}

// ---------------------------------------------------------------- B-fragment build
// One thread per (column, synapse-pair); windows built ONCE globally (no
// duplication), predicated table gathers (p~0.42 active) -> low LDS pipe cost.
// Write layout: slot((kk*NCOL+col)*4+sp) of 16B -> GEMM reads 1KB/wave contiguous.
__global__ __launch_bounds__(256) void k_bbuild(
    const uint32_t* __restrict__ xbT,
    const int*      __restrict__ wk,
    uint4*          __restrict__ Bg)
{
    __shared__ uint2 T0[2048];           // taps 0..10 sums, packed u8 x8 (per weight)
    __shared__ uint2 T1[1024];           // taps 11..20
    __shared__ uint2 tapv[21];

    const int tid = threadIdx.x;
    if (tid < 21) {
        uint32_t lo = 0, hi = 0;
        for (int q = 0; q < 4; ++q) {
            lo |= ((uint32_t)wk[q * 21 + tid]) << (8 * q);
            hi |= ((uint32_t)wk[(q + 4) * 21 + tid]) << (8 * q);
        }
        tapv[tid] = make_uint2(lo, hi);
    }
    __syncthreads();
    for (int e = tid; e < 3072; e += 256) {
        int base_t = (e < 2048) ? 0 : 11;
        uint32_t mm = (e < 2048) ? e : (e - 2048);
        uint2 a = make_uint2(0u, 0u);
        while (mm) {
            int p = __builtin_ctz(mm);
            uint2 tv = tapv[base_t + p];
            a.x += tv.x; a.y += tv.y;
            mm &= mm - 1;
        }
        if (e < 2048) T0[e] = a; else T1[e - 2048] = a;
    }

    const int col = blockIdx.x * 64 + (tid >> 2);      // sp-minor: coalesced writes
    const int sp  = tid & 3;
    int b  = col / TPAD, t = col - b * TPAD;
    int bp = t + 11;                                   // window covers flat bits bp..bp+20
    const uint32_t xbase = (uint32_t)((b * XW2 + (bp >> 5)) * SYN + sp * 2);
    const uint32_t xsh   = (uint32_t)(bp & 31);
    __syncthreads();                                   // tables ready

    const int kk0 = blockIdx.y * 49, kk1 = kk0 + 49;
    for (int kk = kk0; kk < kk1; ++kk) {
        const uint2* px = (const uint2*)(xbT + xbase + kk * 8);
        uint2 lo = px[0];                              // word w  : (s0, s1)
        uint2 hi = px[SYN / 2];                        // word w+1: (s0, s1)
        uint32_t w0 = __builtin_amdgcn_alignbit(hi.x, lo.x, xsh) & 0x1FFFFFu;
        uint32_t w1 = __builtin_amdgcn_alignbit(hi.y, lo.y, xsh) & 0x1FFFFFu;
        uint32_t l0 = w0 & 2047u, h0 = w0 >> 11;
        uint32_t l1 = w1 & 2047u, h1 = w1 >> 11;
        uint2 a0 = make_uint2(0u, 0u), a1 = make_uint2(0u, 0u);
        if (l0) { uint2 u = T0[l0]; a0.x += u.x; a0.y += u.y; }
        if (h0) { uint2 v = T1[h0]; a0.x += v.x; a0.y += v.y; }
        if (l1) { uint2 u = T0[l1]; a1.x += u.x; a1.y += u.y; }
        if (h1) { uint2 v = T1[h1]; a1.x += v.x; a1.y += v.y; }
        Bg[(size_t)(kk * NCOL + col) * 4 + sp] = make_uint4(a0.x, a0.y, a1.x, a1.y);
    }
}

// ---------------------------------------------------------------- pure GEMM + argmax
// Barrier-free, no LDS in K-loop. 1-D grid, XCD-sibling swizzle (B L2-reuse,
// verified R3). R9: fit 128-reg HW quantum for 4 waves/SIMD (m69: occupancy
// steps at 64/128/256 -- R8 proved 144 regs => still 2/SIMD). Working set:
// acc 64 AGPR + af single-buffer 32 (A is XCD-L2-resident, TLP covers ~300cy)
// + bf double-buffer 16 (B is the HBM-latency stream) + ~10 misc = ~122 <= 128.
// 4 waves/SIMD => ~1300cy natural coverage >= B-miss latency.
__global__ __launch_bounds__(256, 4) void k_gemm2(
    const i32x4* __restrict__ Apk4,
    const i32x4* __restrict__ Bg4,
    unsigned long long* __restrict__ partial)
{
    __shared__ unsigned long long red[128 * 4];

    const int tid  = threadIdx.x;
    const int lane = tid & 63;
    const int wn   = tid >> 6;           // 4 col-groups of 32
    const int quad = lane >> 4, l15 = lane & 15;

    // phys -> (rowblk, colblk): xcd = phys&7; j = phys>>3 (0..131);
    // colblk = xcd*33 + (j>>2)  (0..263), rowblk = j&3.
    const int phys   = blockIdx.x;
    const int xcd    = phys & 7;
    const int jb     = phys >> 3;
    const int colblk = xcd * 33 + (jb >> 2);
    const int rowblk = jb & 3;

    const int m0   = rowblk * 128;
    const int col0 = colblk * 128;
    const int rb0  = rowblk * 8;
    const int cb   = col0 + wn * 32 + l15;   // j=0 column of this lane

    // 32-bit element offsets (Apk: 200704 slots; Bg: 13.2M slots -- both << 2^32)
    const uint32_t pa0 = (uint32_t)(rb0 * 64 + lane);       // + kk*2048 + i*64
    const uint32_t pb0 = (uint32_t)(cb * 4 + quad);         // + kk*NCOL*4 (+64 for j=1)

    i32x4 acc[8][2];
#pragma unroll
    for (int i = 0; i < 8; ++i)
#pragma unroll
        for (int jj = 0; jj < 2; ++jj) { i32x4 z = {0, 0, 0, 0}; acc[i][jj] = z; }

    i32x4 af[8], bfA[2], bfB[2];
    // prologue: B first (longest latency), then A(kk=0)
    bfA[0] = Bg4[pb0];
    bfA[1] = Bg4[pb0 + 64];
    bfB[0] = Bg4[pb0 + (uint32_t)NCOL * 4];
    bfB[1] = Bg4[pb0 + (uint32_t)NCOL * 4 + 64];
#pragma unroll
    for (int i = 0; i < 8; ++i) af[i] = Apk4[pa0 + i * 64];

    for (int kk = 0; kk < NKK - 2; kk += 2) {
        // compute kk from af + bfA
#pragma unroll
        for (int i = 0; i < 8; ++i)
#pragma unroll
            for (int jj = 0; jj < 2; ++jj)
                acc[i][jj] = __builtin_amdgcn_mfma_i32_16x16x64_i8(af[i], bfA[jj], acc[i][jj], 0, 0, 0);
        // refill bfA with kk+2 (2-kk slack); then af for kk+1 (consumed next)
        bfA[0] = Bg4[pb0 + (uint32_t)(kk + 2) * (NCOL * 4)];
        bfA[1] = Bg4[pb0 + (uint32_t)(kk + 2) * (NCOL * 4) + 64];
#pragma unroll
        for (int i = 0; i < 8; ++i) af[i] = Apk4[pa0 + (uint32_t)(kk + 1) * 2048 + i * 64];
        // compute kk+1 from af + bfB
#pragma unroll
        for (int i = 0; i < 8; ++i)
#pragma unroll
            for (int jj = 0; jj < 2; ++jj)
                acc[i][jj] = __builtin_amdgcn_mfma_i32_16x16x64_i8(af[i], bfB[jj], acc[i][jj], 0, 0, 0);
        // refill bfB with kk+3; then af for kk+2
        bfB[0] = Bg4[pb0 + (uint32_t)(kk + 3) * (NCOL * 4)];
        bfB[1] = Bg4[pb0 + (uint32_t)(kk + 3) * (NCOL * 4) + 64];
#pragma unroll
        for (int i = 0; i < 8; ++i) af[i] = Apk4[pa0 + (uint32_t)(kk + 2) * 2048 + i * 64];
    }
    // tail: kk = 96 (af current + bfA), then 97 (reload af + bfB)
#pragma unroll
    for (int i = 0; i < 8; ++i)
#pragma unroll
        for (int jj = 0; jj < 2; ++jj)
            acc[i][jj] = __builtin_amdgcn_mfma_i32_16x16x64_i8(af[i], bfA[jj], acc[i][jj], 0, 0, 0);
#pragma unroll
    for (int i = 0; i < 8; ++i) af[i] = Apk4[pa0 + (uint32_t)97 * 2048 + i * 64];
#pragma unroll
    for (int i = 0; i < 8; ++i)
#pragma unroll
        for (int jj = 0; jj < 2; ++jj)
            acc[i][jj] = __builtin_amdgcn_mfma_i32_16x16x64_i8(af[i], bfB[jj], acc[i][jj], 0, 0, 0);

    // epilogue: per-lane best over its 32 rows, then cross-quad via LDS
#pragma unroll
    for (int jj = 0; jj < 2; ++jj) {
        unsigned long long bp = 0ull;
#pragma unroll
        for (int i = 0; i < 8; ++i)
#pragma unroll
            for (int r = 0; r < 4; ++r) {
                int grow = m0 + i * 16 + quad * 4 + r;
                unsigned long long pk =
                    (((unsigned long long)(uint32_t)acc[i][jj][r]) << 32) |
                    (unsigned long long)(uint32_t)(511 - grow);
                bp = pk > bp ? pk : bp;
            }
        red[(wn * 32 + jj * 16 + l15) * 4 + quad] = bp;
    }
    __syncthreads();
    if (tid < 128) {
        unsigned long long b = red[tid * 4];
#pragma unroll
        for (int u = 1; u < 4; ++u) {
            unsigned long long v = red[tid * 4 + u];
            b = v > b ? v : b;
        }
        atomicMax(&partial[col0 + tid], b);
    }
}

// ---------------------------------------------------------------- fused fallback (R0, verified 438us)
__global__ __launch_bounds__(256) void k_gemm_fused(
    const i32x4*    __restrict__ Apk4,
    const uint32_t* __restrict__ xbT,
    const int*      __restrict__ wk,
    unsigned long long* __restrict__ partial)
{
    __shared__ uint2 T0[2048];
    __shared__ uint2 T1[1024];
    __shared__ unsigned long long red[128 * 4];
    __shared__ uint2 tapv[21];

    const int tid  = threadIdx.x;
    const int lane = tid & 63;
    const int wn   = tid >> 6;
    const int quad = lane >> 4, l15 = lane & 15;
    const int m0   = blockIdx.x * 128;
    const int col0 = blockIdx.y * 128;
    const int rb0  = blockIdx.x * 8;

    if (tid < 21) {
        uint32_t lo = 0, hi = 0;
        for (int q = 0; q < 4; ++q) {
            lo |= ((uint32_t)wk[q * 21 + tid]) << (8 * q);
            hi |= ((uint32_t)wk[(q + 4) * 21 + tid]) << (8 * q);
        }
        tapv[tid] = make_uint2(lo, hi);
    }
    __syncthreads();
    for (int e = tid; e < 3072; e += 256) {
        int base_t = (e < 2048) ? 0 : 11;
        uint32_t mm = (e < 2048) ? e : (e - 2048);
        uint2 a = make_uint2(0u, 0u);
        while (mm) {
            int p = __builtin_ctz(mm);
            uint2 tv = tapv[base_t + p];
            a.x += tv.x; a.y += tv.y;
            mm &= mm - 1;
        }
        if (e < 2048) T0[e] = a; else T1[e - 2048] = a;
    }

    uint32_t base[2]; uint32_t sh[2];
#pragma unroll
    for (int j = 0; j < 2; ++j) {
        int c = col0 + wn * 32 + j * 16 + l15;
        int b = c / TPAD, t = c - b * TPAD;
        int bp = t + 11;
        base[j] = (uint32_t)((b * XW2 + (bp >> 5)) * SYN + quad * 2);
        sh[j]   = (uint32_t)(bp & 31);
    }
    __syncthreads();

    i32x4 acc[8][2];
#pragma unroll
    for (int i = 0; i < 8; ++i)
#pragma unroll
        for (int j = 0; j < 2; ++j) { i32x4 z = {0, 0, 0, 0}; acc[i][j] = z; }

    for (int kk = 0; kk < NKK; ++kk) {
        i32x4 af[8];
#pragma unroll
        for (int i = 0; i < 8; ++i)
            af[i] = Apk4[(size_t)(kk * 32 + rb0 + i) * 64 + lane];
        i32x4 bf[2];
#pragma unroll
        for (int j = 0; j < 2; ++j) {
            const uint2* px = (const uint2*)(xbT + base[j] + kk * 8);
            uint2 lo = px[0];
            uint2 hi = px[SYN / 2];
            uint32_t win0 = __builtin_amdgcn_alignbit(hi.x, lo.x, sh[j]) & 0x1FFFFFu;
            uint32_t win1 = __builtin_amdgcn_alignbit(hi.y, lo.y, sh[j]) & 0x1FFFFFu;
            uint2 u0 = T0[win0 & 2047], v0 = T1[win0 >> 11];
            uint2 u1 = T0[win1 & 2047], v1 = T1[win1 >> 11];
            i32x4 bb;
            bb[0] = (int)(u0.x + v0.x); bb[1] = (int)(u0.y + v0.y);
            bb[2] = (int)(u1.x + v1.x); bb[3] = (int)(u1.y + v1.y);
            bf[j] = bb;
        }
#pragma unroll
        for (int i = 0; i < 8; ++i)
#pragma unroll
            for (int j = 0; j < 2; ++j)
                acc[i][j] = __builtin_amdgcn_mfma_i32_16x16x64_i8(af[i], bf[j], acc[i][j], 0, 0, 0);
    }

#pragma unroll
    for (int j = 0; j < 2; ++j) {
        unsigned long long bp = 0ull;
#pragma unroll
        for (int i = 0; i < 8; ++i)
#pragma unroll
            for (int r = 0; r < 4; ++r) {
                int grow = m0 + i * 16 + quad * 4 + r;
                unsigned long long pk =
                    (((unsigned long long)(uint32_t)acc[i][j][r]) << 32) |
                    (unsigned long long)(uint32_t)(511 - grow);
                bp = pk > bp ? pk : bp;
            }
        red[(wn * 32 + j * 16 + l15) * 4 + quad] = bp;
    }
    __syncthreads();
    if (tid < 128) {
        unsigned long long b = red[tid * 4];
#pragma unroll
        for (int u = 1; u < 4; ++u) {
            unsigned long long v = red[tid * 4 + u];
            b = v > b ? v : b;
        }
        atomicMax(&partial[col0 + tid], b);
    }
}

// ---------------------------------------------------------------- fire ballot
__global__ void k_fire(const unsigned long long* __restrict__ partial,
                       int* __restrict__ argT, unsigned long long* __restrict__ fireM) {
    int id   = blockIdx.x * 4 + (threadIdx.x >> 6);   // 576 = 64 b x 9 chunks
    int lane = threadIdx.x & 63;
    int b    = id / 9, ch = id - b * 9;
    int t    = ch * 64 + lane;
    int col  = b * TPAD + (t < TPAD ? t : TPAD - 1);
    unsigned long long pv = partial[col];
    int best = (int)(pv >> 32);
    int arg  = 511 - (int)(pv & 0xFFFFFFFFull);
    argT[id * 64 + lane] = arg;
    unsigned long long f = __ballot((t < TP) && (best > 40));
    if (lane == 0) fireM[id] = f;
}

// ---------------------------------------------------------------- depression walk
__global__ void k_scan(const unsigned long long* __restrict__ fireM,
                       const int* __restrict__ argT, float* __restrict__ out) {
    int b = threadIdx.x;  // 64 lanes = 64 batches
    unsigned long long fm[9];
#pragma unroll
    for (int c = 0; c < 9; ++c) fm[c] = fireM[b * 9 + c];
    unsigned short ts[26];
    int nf = 0, dep = 0;
    for (int c = 0; c < 9; ++c) {
        unsigned long long mm = fm[c];
        int pos = 0;
        while (pos < 64) {
            if (dep > 0) {
                int adv = dep < (64 - pos) ? dep : (64 - pos);
                dep -= adv; pos += adv; mm >>= adv;    // adv <= 21 < 64
                continue;
            }
            if (mm == 0) break;
            int z = __builtin_ctzll(mm);
            pos += z; mm >>= z;
            ts[nf++] = (unsigned short)(c * 64 + pos);
            dep = 21; ++pos; mm >>= 1;
        }
    }
    for (int i = 0; i < nf; ++i) {
        int t = ts[i];
        int a = argT[(b * 9 + (t >> 6)) * 64 + (t & 63)];
        out[(size_t)b * (NEURONS * TP) + (size_t)a * TP + t] = 1.0f;
    }
}

extern "C" void kernel_launch(void* const* d_in, const int* in_sizes, int n_in,
                              void* d_out, int out_size, void* d_ws, size_t ws_size,
                              hipStream_t stream) {
    const float* x      = (const float*)d_in[0];
    const int*   weight = (const int*)d_in[1];
    const int*   wk     = (const int*)d_in[2];

    char* ws = (char*)d_ws;
    uint2*              Apk     = (uint2*)(ws);                        // 3,211,264 B
    uint32_t*           xbT     = (uint32_t*)(ws + 3211264);           // 3,612,672 B
    unsigned long long* partial = (unsigned long long*)(ws + 6823936); //   270,336 B
    int*                argT    = (int*)(ws + 7094272);                //   147,456 B
    unsigned long long* fireM   = (unsigned long long*)(ws + 7241728); //     4,608 B
    uint4*              Bg      = (uint4*)(ws + 7246336);              // 211,746,816 B
    const size_t WS_SPLIT_NEED = 7246336ull + 211746816ull;            // ~219 MB

    float* out = (float*)d_out;

    hipMemsetAsync(out, 0, (size_t)out_size * 4, stream);
    hipMemsetAsync(partial, 0, NCOL * 8, stream);
    k_apack<<<1568, 256, 0, stream>>>(weight, Apk);
    k_xbitsT<<<3136, 256, 0, stream>>>(x, xbT);
    if (ws_size >= WS_SPLIT_NEED) {
        k_bbuild<<<dim3(528, 2), 256, 0, stream>>>(xbT, wk, Bg);
        k_gemm2<<<1056, 256, 0, stream>>>((const i32x4*)Apk, (const i32x4*)Bg, partial);
    } else {
        k_gemm_fused<<<dim3(4, NCOL / 128), 256, 0, stream>>>((const i32x4*)Apk, xbT, wk, partial);
    }
    k_fire<<<144, 256, 0, stream>>>(partial, argT, fireM);
    k_scan<<<1, 64, 0, stream>>>(fireM, argT, out);
}

// Round 10
// 462.425 us; speedup vs baseline: 1.0158x; 1.0158x over previous
//
#include <hip/hip_runtime.h>
#include <stdint.h>

#define NEURONS 512
#define SYN     784
#define TIN     500
#define TP      522
#define TPAD    528
#define BATCH   64
#define NCOL    (BATCH*TPAD)   // 33792
#define XW2     18             // xbT words per (b,*,s): word0 guard, 1..16 data, 17 guard
#define NKK     98             // K iterations (6272 / 64)

typedef int i32x4 __attribute__((ext_vector_type(4)));

__device__ __forceinline__ void load_lds16(const i32x4* g, i32x4* l) {
    __builtin_amdgcn_global_load_lds(
        (const __attribute__((address_space(1))) void*)g,
        (__attribute__((address_space(3))) void*)l,
        16, 0, 0);
}

// ---------------------------------------------------------------- A pack
// One-hot int8 weights, MFMA-fragment-packed (verified R3/R4):
// uint2 slot u <-> (kk, rowblk, quad, m=l15, half): byte k = s*8+w mapping.
__global__ void k_apack(const int* __restrict__ w, uint2* __restrict__ apk) {
    int u = blockIdx.x * 256 + threadIdx.x;            // 401408 slots
    int half = u & 1, m = (u >> 1) & 15, quad = (u >> 5) & 3;
    int rowblk = (u >> 7) & 31, kk = u >> 12;
    int n = rowblk * 16 + m;
    int s = kk * 8 + quad * 2 + half;
    int wv = w[n * SYN + s];
    uint2 v;
    v.x = (wv < 4)  ? (1u << (8 * wv))       : 0u;
    v.y = (wv >= 4) ? (1u << (8 * (wv - 4))) : 0u;
    apk[u] = v;
}

// ---------------------------------------------------------------- spike bits, transposed
__global__ void k_xbitsT(const float* __restrict__ x, uint32_t* __restrict__ xbT) {
    __shared__ unsigned char nib[16][128];
    int tid = threadIdx.x;
    int r0  = blockIdx.x * 16;                         // 3136 blocks, 784%16==0 -> b uniform
    for (int e = tid; e < 2048; e += 256) {
        int row = e >> 7, q4 = e & 127;
        unsigned char v = 0;
        if (q4 < 125) {
            float4 f = *(const float4*)(x + (size_t)(r0 + row) * TIN + q4 * 4);
            v = (unsigned char)((f.x != 0.f) | ((f.y != 0.f) << 1) |
                                ((f.z != 0.f) << 2) | ((f.w != 0.f) << 3));
        }
        nib[row][q4] = v;
    }
    __syncthreads();
    int row = tid >> 4, d = tid & 15;
    uint64_t u = *(const uint64_t*)&nib[row][d * 8];
    uint32_t wd = 0;
#pragma unroll
    for (int q = 0; q < 8; ++q)
        wd |= ((uint32_t)((u >> (8 * q)) & 0xFull)) << (4 * q);
    if (d == 15) wd &= 0xFFFFFu;                       // taus 480..499 only
    int grow = r0 + row;
    int b = grow / SYN, s = grow - b * SYN;
    xbT[(size_t)(b * XW2 + 1 + d) * SYN + s] = wd;
    if (d == 0) {
        xbT[(size_t)(b * XW2) * SYN + s] = 0u;         // guard word 0
        xbT[(size_t)(b * XW2 + 17) * SYN + s] = 0u;    // guard word 17
    }
}

// ---------------------------------------------------------------- B-fragment build
// One thread per (column, synapse-pair); windows built ONCE globally.
// Write layout: slot((kk*NCOL+col)*4+sp) of 16B.
__global__ __launch_bounds__(256) void k_bbuild(
    const uint32_t* __restrict__ xbT,
    const int*      __restrict__ wk,
    uint4*          __restrict__ Bg)
{
    __shared__ uint2 T0[2048];           // taps 0..10 sums, packed u8 x8 (per weight)
    __shared__ uint2 T1[1024];           // taps 11..20
    __shared__ uint2 tapv[21];

    const int tid = threadIdx.x;
    if (tid < 21) {
        uint32_t lo = 0, hi = 0;
        for (int q = 0; q < 4; ++q) {
            lo |= ((uint32_t)wk[q * 21 + tid]) << (8 * q);
            hi |= ((uint32_t)wk[(q + 4) * 21 + tid]) << (8 * q);
        }
        tapv[tid] = make_uint2(lo, hi);
    }
    __syncthreads();
    for (int e = tid; e < 3072; e += 256) {
        int base_t = (e < 2048) ? 0 : 11;
        uint32_t mm = (e < 2048) ? e : (e - 2048);
        uint2 a = make_uint2(0u, 0u);
        while (mm) {
            int p = __builtin_ctz(mm);
            uint2 tv = tapv[base_t + p];
            a.x += tv.x; a.y += tv.y;
            mm &= mm - 1;
        }
        if (e < 2048) T0[e] = a; else T1[e - 2048] = a;
    }

    const int col = blockIdx.x * 64 + (tid >> 2);      // sp-minor: coalesced writes
    const int sp  = tid & 3;
    int b  = col / TPAD, t = col - b * TPAD;
    int bp = t + 11;                                   // window covers flat bits bp..bp+20
    const uint32_t xbase = (uint32_t)((b * XW2 + (bp >> 5)) * SYN + sp * 2);
    const uint32_t xsh   = (uint32_t)(bp & 31);
    __syncthreads();                                   // tables ready

    const int kk0 = blockIdx.y * 49, kk1 = kk0 + 49;
    for (int kk = kk0; kk < kk1; ++kk) {
        const uint2* px = (const uint2*)(xbT + xbase + kk * 8);
        uint2 lo = px[0];                              // word w  : (s0, s1)
        uint2 hi = px[SYN / 2];                        // word w+1: (s0, s1)
        uint32_t w0 = __builtin_amdgcn_alignbit(hi.x, lo.x, xsh) & 0x1FFFFFu;
        uint32_t w1 = __builtin_amdgcn_alignbit(hi.y, lo.y, xsh) & 0x1FFFFFu;
        uint32_t l0 = w0 & 2047u, h0 = w0 >> 11;
        uint32_t l1 = w1 & 2047u, h1 = w1 >> 11;
        uint2 a0 = make_uint2(0u, 0u), a1 = make_uint2(0u, 0u);
        if (l0) { uint2 u = T0[l0]; a0.x += u.x; a0.y += u.y; }
        if (h0) { uint2 v = T1[h0]; a0.x += v.x; a0.y += v.y; }
        if (l1) { uint2 u = T0[l1]; a1.x += u.x; a1.y += u.y; }
        if (h1) { uint2 v = T1[h1]; a1.x += v.x; a1.y += v.y; }
        Bg[(size_t)(kk * NCOL + col) * 4 + sp] = make_uint4(a0.x, a0.y, a1.x, a1.y);
    }
}

// ---------------------------------------------------------------- GEMM + argmax, DMA-staged
// R10: global_load_lds pipeline (T3/T4 minimum 2-phase). 3 LDS bufs x (8KB A +
// 8KB B), prefetch depth 2, counted vmcnt(4) + ONE raw barrier per kk (vmcnt(0)
// only at last iter). A staged ONCE per block (kills the 4x duplicate A loads);
// DMA queue holds in-flight loads -> no VGPR pipeline, no occupancy dependence.
// Per-lane global srcs pre-arranged so DMA's (base + lane*16) lands in exact
// fragment order; ds_read_b128 at lane*16 = conflict-free, layout == R4/R8.
__global__ __launch_bounds__(256) void k_gemm3(
    const i32x4* __restrict__ Apk4,
    const i32x4* __restrict__ Bg4,
    unsigned long long* __restrict__ partial)
{
    __shared__ i32x4 bufA[3][512];      // [buf][chunk c*64 + lane], c=0..7 <-> A slot rb0+c
    __shared__ i32x4 bufB[3][512];      // [buf][chunk j*64 + lane], j=0..7 <-> cols j*16..j*16+15
    __shared__ unsigned long long red[128 * 4];

    const int tid  = threadIdx.x;
    const int lane = tid & 63;
    const int wn   = tid >> 6;           // 4 col-groups of 32
    const int quad = lane >> 4, l15 = lane & 15;

    // phys -> (rowblk, colblk): XCD-sibling swizzle (verified R3)
    const int phys   = blockIdx.x;
    const int xcd    = phys & 7;
    const int jb     = phys >> 3;
    const int colblk = xcd * 33 + (jb >> 2);
    const int rowblk = jb & 3;

    const int m0   = rowblk * 128;
    const int col0 = colblk * 128;
    const int rb0  = rowblk * 8;

    // staging chunk offsets for THIS wave (chunks wn*2, wn*2+1 of A and B)
    const uint32_t aoff0 = (uint32_t)((rb0 + wn * 2 + 0) * 64 + lane);
    const uint32_t aoff1 = (uint32_t)((rb0 + wn * 2 + 1) * 64 + lane);
    const uint32_t boff0 = (uint32_t)((col0 + (wn * 2 + 0) * 16 + l15) * 4 + quad);
    const uint32_t boff1 = (uint32_t)((col0 + (wn * 2 + 1) * 16 + l15) * 4 + quad);

#define STAGE(kk_, b_) do {                                                    \
        const i32x4* ga = Apk4 + (size_t)(kk_) * 2048;                         \
        const i32x4* gb = Bg4 + (size_t)(kk_) * (NCOL * 4);                    \
        load_lds16(ga + aoff0, &bufA[b_][(wn * 2 + 0) * 64]);                  \
        load_lds16(ga + aoff1, &bufA[b_][(wn * 2 + 1) * 64]);                  \
        load_lds16(gb + boff0, &bufB[b_][(wn * 2 + 0) * 64]);                  \
        load_lds16(gb + boff1, &bufB[b_][(wn * 2 + 1) * 64]);                  \
    } while (0)

    i32x4 acc[8][2];
#pragma unroll
    for (int i = 0; i < 8; ++i)
#pragma unroll
        for (int jj = 0; jj < 2; ++jj) { i32x4 z = {0, 0, 0, 0}; acc[i][jj] = z; }

    // prologue: stage kk=0,1 (8 instr/wave outstanding)
    STAGE(0, 0);
    STAGE(1, 1);

    for (int kk = 0; kk < NKK; ++kk) {
        // wait stage(kk) landed: outstanding = {stage(kk), stage(kk+1)} = 8 -> vmcnt(4).
        // last iter: only stage(97)=4 outstanding -> need vmcnt(0).
        if (kk < NKK - 1) { asm volatile("s_waitcnt vmcnt(4)" ::: "memory"); }
        else              { asm volatile("s_waitcnt vmcnt(0)" ::: "memory"); }
        // entry barrier: all waves' stage(kk) landed AND all waves done reading
        // buf[kk-1] (their MFMAs consumed the ds_reads before their own vmcnt).
        __builtin_amdgcn_s_barrier();
        // issue stage(kk+2) into buf[(kk+2)%3] == buf[(kk-1)%3] (safe per above)
        if (kk + 2 < NKK) STAGE(kk + 2, (kk + 2) % 3);

        const int b = kk % 3;
        i32x4 af[8], bf[2];
#pragma unroll
        for (int i = 0; i < 8; ++i) af[i] = bufA[b][i * 64 + lane];
#pragma unroll
        for (int jj = 0; jj < 2; ++jj) bf[jj] = bufB[b][(wn * 2 + jj) * 64 + lane];
#pragma unroll
        for (int i = 0; i < 8; ++i)
#pragma unroll
            for (int jj = 0; jj < 2; ++jj)
                acc[i][jj] = __builtin_amdgcn_mfma_i32_16x16x64_i8(af[i], bf[jj], acc[i][jj], 0, 0, 0);
    }
#undef STAGE

    // epilogue: per-lane best over its 32 rows, then cross-quad via LDS
#pragma unroll
    for (int jj = 0; jj < 2; ++jj) {
        unsigned long long bp = 0ull;
#pragma unroll
        for (int i = 0; i < 8; ++i)
#pragma unroll
            for (int r = 0; r < 4; ++r) {
                int grow = m0 + i * 16 + quad * 4 + r;
                unsigned long long pk =
                    (((unsigned long long)(uint32_t)acc[i][jj][r]) << 32) |
                    (unsigned long long)(uint32_t)(511 - grow);
                bp = pk > bp ? pk : bp;
            }
        red[(wn * 32 + jj * 16 + l15) * 4 + quad] = bp;
    }
    __syncthreads();
    if (tid < 128) {
        unsigned long long b = red[tid * 4];
#pragma unroll
        for (int u = 1; u < 4; ++u) {
            unsigned long long v = red[tid * 4 + u];
            b = v > b ? v : b;
        }
        atomicMax(&partial[col0 + tid], b);
    }
}

// ---------------------------------------------------------------- fused fallback (R0, verified 438us)
__global__ __launch_bounds__(256) void k_gemm_fused(
    const i32x4*    __restrict__ Apk4,
    const uint32_t* __restrict__ xbT,
    const int*      __restrict__ wk,
    unsigned long long* __restrict__ partial)
{
    __shared__ uint2 T0[2048];
    __shared__ uint2 T1[1024];
    __shared__ unsigned long long red[128 * 4];
    __shared__ uint2 tapv[21];

    const int tid  = threadIdx.x;
    const int lane = tid & 63;
    const int wn   = tid >> 6;
    const int quad = lane >> 4, l15 = lane & 15;
    const int m0   = blockIdx.x * 128;
    const int col0 = blockIdx.y * 128;
    const int rb0  = blockIdx.x * 8;

    if (tid < 21) {
        uint32_t lo = 0, hi = 0;
        for (int q = 0; q < 4; ++q) {
            lo |= ((uint32_t)wk[q * 21 + tid]) << (8 * q);
            hi |= ((uint32_t)wk[(q + 4) * 21 + tid]) << (8 * q);
        }
        tapv[tid] = make_uint2(lo, hi);
    }
    __syncthreads();
    for (int e = tid; e < 3072; e += 256) {
        int base_t = (e < 2048) ? 0 : 11;
        uint32_t mm = (e < 2048) ? e : (e - 2048);
        uint2 a = make_uint2(0u, 0u);
        while (mm) {
            int p = __builtin_ctz(mm);
            uint2 tv = tapv[base_t + p];
            a.x += tv.x; a.y += tv.y;
            mm &= mm - 1;
        }
        if (e < 2048) T0[e] = a; else T1[e - 2048] = a;
    }

    uint32_t base[2]; uint32_t sh[2];
#pragma unroll
    for (int j = 0; j < 2; ++j) {
        int c = col0 + wn * 32 + j * 16 + l15;
        int b = c / TPAD, t = c - b * TPAD;
        int bp = t + 11;
        base[j] = (uint32_t)((b * XW2 + (bp >> 5)) * SYN + quad * 2);
        sh[j]   = (uint32_t)(bp & 31);
    }
    __syncthreads();

    i32x4 acc[8][2];
#pragma unroll
    for (int i = 0; i < 8; ++i)
#pragma unroll
        for (int j = 0; j < 2; ++j) { i32x4 z = {0, 0, 0, 0}; acc[i][j] = z; }

    for (int kk = 0; kk < NKK; ++kk) {
        i32x4 af[8];
#pragma unroll
        for (int i = 0; i < 8; ++i)
            af[i] = Apk4[(size_t)(kk * 32 + rb0 + i) * 64 + lane];
        i32x4 bf[2];
#pragma unroll
        for (int j = 0; j < 2; ++j) {
            const uint2* px = (const uint2*)(xbT + base[j] + kk * 8);
            uint2 lo = px[0];
            uint2 hi = px[SYN / 2];
            uint32_t win0 = __builtin_amdgcn_alignbit(hi.x, lo.x, sh[j]) & 0x1FFFFFu;
            uint32_t win1 = __builtin_amdgcn_alignbit(hi.y, lo.y, sh[j]) & 0x1FFFFFu;
            uint2 u0 = T0[win0 & 2047], v0 = T1[win0 >> 11];
            uint2 u1 = T0[win1 & 2047], v1 = T1[win1 >> 11];
            i32x4 bb;
            bb[0] = (int)(u0.x + v0.x); bb[1] = (int)(u0.y + v0.y);
            bb[2] = (int)(u1.x + v1.x); bb[3] = (int)(u1.y + v1.y);
            bf[j] = bb;
        }
#pragma unroll
        for (int i = 0; i < 8; ++i)
#pragma unroll
            for (int j = 0; j < 2; ++j)
                acc[i][j] = __builtin_amdgcn_mfma_i32_16x16x64_i8(af[i], bf[j], acc[i][j], 0, 0, 0);
    }

#pragma unroll
    for (int j = 0; j < 2; ++j) {
        unsigned long long bp = 0ull;
#pragma unroll
        for (int i = 0; i < 8; ++i)
#pragma unroll
            for (int r = 0; r < 4; ++r) {
                int grow = m0 + i * 16 + quad * 4 + r;
                unsigned long long pk =
                    (((unsigned long long)(uint32_t)acc[i][j][r]) << 32) |
                    (unsigned long long)(uint32_t)(511 - grow);
                bp = pk > bp ? pk : bp;
            }
        red[(wn * 32 + j * 16 + l15) * 4 + quad] = bp;
    }
    __syncthreads();
    if (tid < 128) {
        unsigned long long b = red[tid * 4];
#pragma unroll
        for (int u = 1; u < 4; ++u) {
            unsigned long long v = red[tid * 4 + u];
            b = v > b ? v : b;
        }
        atomicMax(&partial[col0 + tid], b);
    }
}

// ---------------------------------------------------------------- fire ballot
__global__ void k_fire(const unsigned long long* __restrict__ partial,
                       int* __restrict__ argT, unsigned long long* __restrict__ fireM) {
    int id   = blockIdx.x * 4 + (threadIdx.x >> 6);   // 576 = 64 b x 9 chunks
    int lane = threadIdx.x & 63;
    int b    = id / 9, ch = id - b * 9;
    int t    = ch * 64 + lane;
    int col  = b * TPAD + (t < TPAD ? t : TPAD - 1);
    unsigned long long pv = partial[col];
    int best = (int)(pv >> 32);
    int arg  = 511 - (int)(pv & 0xFFFFFFFFull);
    argT[id * 64 + lane] = arg;
    unsigned long long f = __ballot((t < TP) && (best > 40));
    if (lane == 0) fireM[id] = f;
}

// ---------------------------------------------------------------- depression walk
__global__ void k_scan(const unsigned long long* __restrict__ fireM,
                       const int* __restrict__ argT, float* __restrict__ out) {
    int b = threadIdx.x;  // 64 lanes = 64 batches
    unsigned long long fm[9];
#pragma unroll
    for (int c = 0; c < 9; ++c) fm[c] = fireM[b * 9 + c];
    unsigned short ts[26];
    int nf = 0, dep = 0;
    for (int c = 0; c < 9; ++c) {
        unsigned long long mm = fm[c];
        int pos = 0;
        while (pos < 64) {
            if (dep > 0) {
                int adv = dep < (64 - pos) ? dep : (64 - pos);
                dep -= adv; pos += adv; mm >>= adv;    // adv <= 21 < 64
                continue;
            }
            if (mm == 0) break;
            int z = __builtin_ctzll(mm);
            pos += z; mm >>= z;
            ts[nf++] = (unsigned short)(c * 64 + pos);
            dep = 21; ++pos; mm >>= 1;
        }
    }
    for (int i = 0; i < nf; ++i) {
        int t = ts[i];
        int a = argT[(b * 9 + (t >> 6)) * 64 + (t & 63)];
        out[(size_t)b * (NEURONS * TP) + (size_t)a * TP + t] = 1.0f;
    }
}

extern "C" void kernel_launch(void* const* d_in, const int* in_sizes, int n_in,
                              void* d_out, int out_size, void* d_ws, size_t ws_size,
                              hipStream_t stream) {
    const float* x      = (const float*)d_in[0];
    const int*   weight = (const int*)d_in[1];
    const int*   wk     = (const int*)d_in[2];

    char* ws = (char*)d_ws;
    uint2*              Apk     = (uint2*)(ws);                        // 3,211,264 B
    uint32_t*           xbT     = (uint32_t*)(ws + 3211264);           // 3,612,672 B
    unsigned long long* partial = (unsigned long long*)(ws + 6823936); //   270,336 B
    int*                argT    = (int*)(ws + 7094272);                //   147,456 B
    unsigned long long* fireM   = (unsigned long long*)(ws + 7241728); //     4,608 B
    uint4*              Bg      = (uint4*)(ws + 7246336);              // 211,746,816 B
    const size_t WS_SPLIT_NEED = 7246336ull + 211746816ull;            // ~219 MB

    float* out = (float*)d_out;

    hipMemsetAsync(out, 0, (size_t)out_size * 4, stream);
    hipMemsetAsync(partial, 0, NCOL * 8, stream);
    k_apack<<<1568, 256, 0, stream>>>(weight, Apk);
    k_xbitsT<<<3136, 256, 0, stream>>>(x, xbT);
    if (ws_size >= WS_SPLIT_NEED) {
        k_bbuild<<<dim3(528, 2), 256, 0, stream>>>(xbT, wk, Bg);
        k_gemm3<<<1056, 256, 0, stream>>>((const i32x4*)Apk, (const i32x4*)Bg, partial);
    } else {
        k_gemm_fused<<<dim3(4, NCOL / 128), 256, 0, stream>>>((const i32x4*)Apk, xbT, wk, partial);
    }
    k_fire<<<144, 256, 0, stream>>>(partial, argT, fireM);
    k_scan<<<1, 64, 0, stream>>>(fireM, argT, out);
}

// Round 11
// 418.221 us; speedup vs baseline: 1.1232x; 1.1057x over previous
//
#include <hip/hip_runtime.h>
#include <stdint.h>

#define NEURONS 512
#define SYN     784
#define TIN     500
#define TP      522
#define TPAD    528
#define BATCH   64
#define NCOL    (BATCH*TPAD)   // 33792
#define XW2     18             // xbT words per (b,*,s): word0 guard, 1..16 data, 17 guard
#define NKK     98             // K iterations (6272 / 64)

typedef int i32x4 __attribute__((ext_vector_type(4)));

// ---------------------------------------------------------------- A pack
// One-hot int8 weights, MFMA-fragment-packed (verified R3/R4):
// uint2 slot u <-> (kk, rowblk, quad, m=l15, half): byte k = s*8+w mapping.
__global__ void k_apack(const int* __restrict__ w, uint2* __restrict__ apk) {
    int u = blockIdx.x * 256 + threadIdx.x;            // 401408 slots
    int half = u & 1, m = (u >> 1) & 15, quad = (u >> 5) & 3;
    int rowblk = (u >> 7) & 31, kk = u >> 12;
    int n = rowblk * 16 + m;
    int s = kk * 8 + quad * 2 + half;
    int wv = w[n * SYN + s];
    uint2 v;
    v.x = (wv < 4)  ? (1u << (8 * wv))       : 0u;
    v.y = (wv >= 4) ? (1u << (8 * (wv - 4))) : 0u;
    apk[u] = v;
}

// ---------------------------------------------------------------- spike bits, transposed
__global__ void k_xbitsT(const float* __restrict__ x, uint32_t* __restrict__ xbT) {
    __shared__ unsigned char nib[16][128];
    int tid = threadIdx.x;
    int r0  = blockIdx.x * 16;                         // 3136 blocks, 784%16==0 -> b uniform
    for (int e = tid; e < 2048; e += 256) {
        int row = e >> 7, q4 = e & 127;
        unsigned char v = 0;
        if (q4 < 125) {
            float4 f = *(const float4*)(x + (size_t)(r0 + row) * TIN + q4 * 4);
            v = (unsigned char)((f.x != 0.f) | ((f.y != 0.f) << 1) |
                                ((f.z != 0.f) << 2) | ((f.w != 0.f) << 3));
        }
        nib[row][q4] = v;
    }
    __syncthreads();
    int row = tid >> 4, d = tid & 15;
    uint64_t u = *(const uint64_t*)&nib[row][d * 8];
    uint32_t wd = 0;
#pragma unroll
    for (int q = 0; q < 8; ++q)
        wd |= ((uint32_t)((u >> (8 * q)) & 0xFull)) << (4 * q);
    if (d == 15) wd &= 0xFFFFFu;                       // taus 480..499 only
    int grow = r0 + row;
    int b = grow / SYN, s = grow - b * SYN;
    xbT[(size_t)(b * XW2 + 1 + d) * SYN + s] = wd;
    if (d == 0) {
        xbT[(size_t)(b * XW2) * SYN + s] = 0u;         // guard word 0
        xbT[(size_t)(b * XW2 + 17) * SYN + s] = 0u;    // guard word 17
    }
}

// ---------------------------------------------------------------- B-fragment build
// One thread per (column, synapse-pair); windows built ONCE globally.
// Write layout: slot((kk*NCOL+col)*4+sp) of 16B.
__global__ __launch_bounds__(256) void k_bbuild(
    const uint32_t* __restrict__ xbT,
    const int*      __restrict__ wk,
    uint4*          __restrict__ Bg)
{
    __shared__ uint2 T0[2048];           // taps 0..10 sums, packed u8 x8 (per weight)
    __shared__ uint2 T1[1024];           // taps 11..20
    __shared__ uint2 tapv[21];

    const int tid = threadIdx.x;
    if (tid < 21) {
        uint32_t lo = 0, hi = 0;
        for (int q = 0; q < 4; ++q) {
            lo |= ((uint32_t)wk[q * 21 + tid]) << (8 * q);
            hi |= ((uint32_t)wk[(q + 4) * 21 + tid]) << (8 * q);
        }
        tapv[tid] = make_uint2(lo, hi);
    }
    __syncthreads();
    for (int e = tid; e < 3072; e += 256) {
        int base_t = (e < 2048) ? 0 : 11;
        uint32_t mm = (e < 2048) ? e : (e - 2048);
        uint2 a = make_uint2(0u, 0u);
        while (mm) {
            int p = __builtin_ctz(mm);
            uint2 tv = tapv[base_t + p];
            a.x += tv.x; a.y += tv.y;
            mm &= mm - 1;
        }
        if (e < 2048) T0[e] = a; else T1[e - 2048] = a;
    }

    const int col = blockIdx.x * 64 + (tid >> 2);      // sp-minor: coalesced writes
    const int sp  = tid & 3;
    int b  = col / TPAD, t = col - b * TPAD;
    int bp = t + 11;                                   // window covers flat bits bp..bp+20
    const uint32_t xbase = (uint32_t)((b * XW2 + (bp >> 5)) * SYN + sp * 2);
    const uint32_t xsh   = (uint32_t)(bp & 31);
    __syncthreads();                                   // tables ready

    const int kk0 = blockIdx.y * 49, kk1 = kk0 + 49;
    for (int kk = kk0; kk < kk1; ++kk) {
        const uint2* px = (const uint2*)(xbT + xbase + kk * 8);
        uint2 lo = px[0];                              // word w  : (s0, s1)
        uint2 hi = px[SYN / 2];                        // word w+1: (s0, s1)
        uint32_t w0 = __builtin_amdgcn_alignbit(hi.x, lo.x, xsh) & 0x1FFFFFu;
        uint32_t w1 = __builtin_amdgcn_alignbit(hi.y, lo.y, xsh) & 0x1FFFFFu;
        uint32_t l0 = w0 & 2047u, h0 = w0 >> 11;
        uint32_t l1 = w1 & 2047u, h1 = w1 >> 11;
        uint2 a0 = make_uint2(0u, 0u), a1 = make_uint2(0u, 0u);
        if (l0) { uint2 u = T0[l0]; a0.x += u.x; a0.y += u.y; }
        if (h0) { uint2 v = T1[h0]; a0.x += v.x; a0.y += v.y; }
        if (l1) { uint2 u = T0[l1]; a1.x += u.x; a1.y += u.y; }
        if (h1) { uint2 v = T1[h1]; a1.x += v.x; a1.y += v.y; }
        Bg[(size_t)(kk * NCOL + col) * 4 + sp] = make_uint4(a0.x, a0.y, a1.x, a1.y);
    }
}

// ---------------------------------------------------------------- pure GEMM + argmax
// Barrier-free, no LDS in K-loop. R11: arithmetic intensity -- wave tile
// 128x32 -> 128x64 (acc[8][4]). Per-wave MFMA/kk 16->32 (652cy), per-block
// traffic/kk 40KB->48KB for 2x work => 375 B/MFMA (1.7x less), and latency
// coverage per wave doubles. Block = 4 waves x 64 cols = 256 cols; grid 528.
// XCD swizzle: p=(phys&7)*66+(phys>>3); colblk=p>>2, rowblk=p&3 (bijective,
// 4 rowblk siblings of a colblk adjacent on one XCD -> B L2-reuse, verified R3).
// Depth-2 register dbuf on BOTH operands (R4/R8 verified schedule).
__global__ __launch_bounds__(256) void k_gemm2(
    const i32x4* __restrict__ Apk4,
    const i32x4* __restrict__ Bg4,
    unsigned long long* __restrict__ partial)
{
    __shared__ unsigned long long red[256 * 4];

    const int tid  = threadIdx.x;
    const int lane = tid & 63;
    const int wn   = tid >> 6;           // 4 col-groups of 64
    const int quad = lane >> 4, l15 = lane & 15;

    const int phys   = blockIdx.x;
    const int p      = (phys & 7) * 66 + (phys >> 3);   // bijective 0..527
    const int colblk = p >> 2;           // 0..131
    const int rowblk = p & 3;

    const int m0   = rowblk * 128;
    const int col0 = colblk * 256;
    const int rb0  = rowblk * 8;
    const int cb   = col0 + wn * 64 + l15;   // jj=0 column of this lane

    // 32-bit element offsets (Apk: 200704 slots; Bg: 13.2M slots)
    const uint32_t pa0 = (uint32_t)(rb0 * 64 + lane);   // + kk*2048 + i*64
    const uint32_t pb0 = (uint32_t)(cb * 4 + quad);     // + kk*NCOL*4 + jj*64

    i32x4 acc[8][4];
#pragma unroll
    for (int i = 0; i < 8; ++i)
#pragma unroll
        for (int jj = 0; jj < 4; ++jj) { i32x4 z = {0, 0, 0, 0}; acc[i][jj] = z; }

    i32x4 afA[8], afB[8], bfA[4], bfB[4];
    // prologue: B first (longest latency)
#pragma unroll
    for (int jj = 0; jj < 4; ++jj) bfA[jj] = Bg4[pb0 + jj * 64];
#pragma unroll
    for (int jj = 0; jj < 4; ++jj) bfB[jj] = Bg4[pb0 + (uint32_t)NCOL * 4 + jj * 64];
#pragma unroll
    for (int i = 0; i < 8; ++i) afA[i] = Apk4[pa0 + i * 64];
#pragma unroll
    for (int i = 0; i < 8; ++i) afB[i] = Apk4[pa0 + 2048 + i * 64];

    for (int kk = 0; kk < NKK - 2; kk += 2) {
        // compute kk from A buffers
#pragma unroll
        for (int i = 0; i < 8; ++i)
#pragma unroll
            for (int jj = 0; jj < 4; ++jj)
                acc[i][jj] = __builtin_amdgcn_mfma_i32_16x16x64_i8(afA[i], bfA[jj], acc[i][jj], 0, 0, 0);
        // refill A-set with kk+2 (B first: longer latency)
#pragma unroll
        for (int jj = 0; jj < 4; ++jj)
            bfA[jj] = Bg4[pb0 + (uint32_t)(kk + 2) * (NCOL * 4) + jj * 64];
#pragma unroll
        for (int i = 0; i < 8; ++i)
            afA[i] = Apk4[pa0 + (uint32_t)(kk + 2) * 2048 + i * 64];
        // compute kk+1 from B buffers
#pragma unroll
        for (int i = 0; i < 8; ++i)
#pragma unroll
            for (int jj = 0; jj < 4; ++jj)
                acc[i][jj] = __builtin_amdgcn_mfma_i32_16x16x64_i8(afB[i], bfB[jj], acc[i][jj], 0, 0, 0);
        // refill B-set with kk+3
#pragma unroll
        for (int jj = 0; jj < 4; ++jj)
            bfB[jj] = Bg4[pb0 + (uint32_t)(kk + 3) * (NCOL * 4) + jj * 64];
#pragma unroll
        for (int i = 0; i < 8; ++i)
            afB[i] = Apk4[pa0 + (uint32_t)(kk + 3) * 2048 + i * 64];
    }
    // tail: kk = 96 (A set), 97 (B set)
#pragma unroll
    for (int i = 0; i < 8; ++i)
#pragma unroll
        for (int jj = 0; jj < 4; ++jj)
            acc[i][jj] = __builtin_amdgcn_mfma_i32_16x16x64_i8(afA[i], bfA[jj], acc[i][jj], 0, 0, 0);
#pragma unroll
    for (int i = 0; i < 8; ++i)
#pragma unroll
        for (int jj = 0; jj < 4; ++jj)
            acc[i][jj] = __builtin_amdgcn_mfma_i32_16x16x64_i8(afB[i], bfB[jj], acc[i][jj], 0, 0, 0);

    // epilogue: per-lane best over its 32 rows per column, cross-quad via LDS
#pragma unroll
    for (int jj = 0; jj < 4; ++jj) {
        unsigned long long bp = 0ull;
#pragma unroll
        for (int i = 0; i < 8; ++i)
#pragma unroll
            for (int r = 0; r < 4; ++r) {
                int grow = m0 + i * 16 + quad * 4 + r;
                unsigned long long pk =
                    (((unsigned long long)(uint32_t)acc[i][jj][r]) << 32) |
                    (unsigned long long)(uint32_t)(511 - grow);
                bp = pk > bp ? pk : bp;
            }
        red[(wn * 64 + jj * 16 + l15) * 4 + quad] = bp;
    }
    __syncthreads();
    {
        unsigned long long b = red[tid * 4];
#pragma unroll
        for (int u = 1; u < 4; ++u) {
            unsigned long long v = red[tid * 4 + u];
            b = v > b ? v : b;
        }
        atomicMax(&partial[col0 + tid], b);
    }
}

// ---------------------------------------------------------------- fused fallback (R0, verified 438us)
__global__ __launch_bounds__(256) void k_gemm_fused(
    const i32x4*    __restrict__ Apk4,
    const uint32_t* __restrict__ xbT,
    const int*      __restrict__ wk,
    unsigned long long* __restrict__ partial)
{
    __shared__ uint2 T0[2048];
    __shared__ uint2 T1[1024];
    __shared__ unsigned long long red[128 * 4];
    __shared__ uint2 tapv[21];

    const int tid  = threadIdx.x;
    const int lane = tid & 63;
    const int wn   = tid >> 6;
    const int quad = lane >> 4, l15 = lane & 15;
    const int m0   = blockIdx.x * 128;
    const int col0 = blockIdx.y * 128;
    const int rb0  = blockIdx.x * 8;

    if (tid < 21) {
        uint32_t lo = 0, hi = 0;
        for (int q = 0; q < 4; ++q) {
            lo |= ((uint32_t)wk[q * 21 + tid]) << (8 * q);
            hi |= ((uint32_t)wk[(q + 4) * 21 + tid]) << (8 * q);
        }
        tapv[tid] = make_uint2(lo, hi);
    }
    __syncthreads();
    for (int e = tid; e < 3072; e += 256) {
        int base_t = (e < 2048) ? 0 : 11;
        uint32_t mm = (e < 2048) ? e : (e - 2048);
        uint2 a = make_uint2(0u, 0u);
        while (mm) {
            int p = __builtin_ctz(mm);
            uint2 tv = tapv[base_t + p];
            a.x += tv.x; a.y += tv.y;
            mm &= mm - 1;
        }
        if (e < 2048) T0[e] = a; else T1[e - 2048] = a;
    }

    uint32_t base[2]; uint32_t sh[2];
#pragma unroll
    for (int j = 0; j < 2; ++j) {
        int c = col0 + wn * 32 + j * 16 + l15;
        int b = c / TPAD, t = c - b * TPAD;
        int bp = t + 11;
        base[j] = (uint32_t)((b * XW2 + (bp >> 5)) * SYN + quad * 2);
        sh[j]   = (uint32_t)(bp & 31);
    }
    __syncthreads();

    i32x4 acc[8][2];
#pragma unroll
    for (int i = 0; i < 8; ++i)
#pragma unroll
        for (int j = 0; j < 2; ++j) { i32x4 z = {0, 0, 0, 0}; acc[i][j] = z; }

    for (int kk = 0; kk < NKK; ++kk) {
        i32x4 af[8];
#pragma unroll
        for (int i = 0; i < 8; ++i)
            af[i] = Apk4[(size_t)(kk * 32 + rb0 + i) * 64 + lane];
        i32x4 bf[2];
#pragma unroll
        for (int j = 0; j < 2; ++j) {
            const uint2* px = (const uint2*)(xbT + base[j] + kk * 8);
            uint2 lo = px[0];
            uint2 hi = px[SYN / 2];
            uint32_t win0 = __builtin_amdgcn_alignbit(hi.x, lo.x, sh[j]) & 0x1FFFFFu;
            uint32_t win1 = __builtin_amdgcn_alignbit(hi.y, lo.y, sh[j]) & 0x1FFFFFu;
            uint2 u0 = T0[win0 & 2047], v0 = T1[win0 >> 11];
            uint2 u1 = T0[win1 & 2047], v1 = T1[win1 >> 11];
            i32x4 bb;
            bb[0] = (int)(u0.x + v0.x); bb[1] = (int)(u0.y + v0.y);
            bb[2] = (int)(u1.x + v1.x); bb[3] = (int)(u1.y + v1.y);
            bf[j] = bb;
        }
#pragma unroll
        for (int i = 0; i < 8; ++i)
#pragma unroll
            for (int j = 0; j < 2; ++j)
                acc[i][j] = __builtin_amdgcn_mfma_i32_16x16x64_i8(af[i], bf[j], acc[i][j], 0, 0, 0);
    }

#pragma unroll
    for (int j = 0; j < 2; ++j) {
        unsigned long long bp = 0ull;
#pragma unroll
        for (int i = 0; i < 8; ++i)
#pragma unroll
            for (int r = 0; r < 4; ++r) {
                int grow = m0 + i * 16 + quad * 4 + r;
                unsigned long long pk =
                    (((unsigned long long)(uint32_t)acc[i][j][r]) << 32) |
                    (unsigned long long)(uint32_t)(511 - grow);
                bp = pk > bp ? pk : bp;
            }
        red[(wn * 32 + j * 16 + l15) * 4 + quad] = bp;
    }
    __syncthreads();
    if (tid < 128) {
        unsigned long long b = red[tid * 4];
#pragma unroll
        for (int u = 1; u < 4; ++u) {
            unsigned long long v = red[tid * 4 + u];
            b = v > b ? v : b;
        }
        atomicMax(&partial[col0 + tid], b);
    }
}

// ---------------------------------------------------------------- fire ballot
__global__ void k_fire(const unsigned long long* __restrict__ partial,
                       int* __restrict__ argT, unsigned long long* __restrict__ fireM) {
    int id   = blockIdx.x * 4 + (threadIdx.x >> 6);   // 576 = 64 b x 9 chunks
    int lane = threadIdx.x & 63;
    int b    = id / 9, ch = id - b * 9;
    int t    = ch * 64 + lane;
    int col  = b * TPAD + (t < TPAD ? t : TPAD - 1);
    unsigned long long pv = partial[col];
    int best = (int)(pv >> 32);
    int arg  = 511 - (int)(pv & 0xFFFFFFFFull);
    argT[id * 64 + lane] = arg;
    unsigned long long f = __ballot((t < TP) && (best > 40));
    if (lane == 0) fireM[id] = f;
}

// ---------------------------------------------------------------- depression walk
__global__ void k_scan(const unsigned long long* __restrict__ fireM,
                       const int* __restrict__ argT, float* __restrict__ out) {
    int b = threadIdx.x;  // 64 lanes = 64 batches
    unsigned long long fm[9];
#pragma unroll
    for (int c = 0; c < 9; ++c) fm[c] = fireM[b * 9 + c];
    unsigned short ts[26];
    int nf = 0, dep = 0;
    for (int c = 0; c < 9; ++c) {
        unsigned long long mm = fm[c];
        int pos = 0;
        while (pos < 64) {
            if (dep > 0) {
                int adv = dep < (64 - pos) ? dep : (64 - pos);
                dep -= adv; pos += adv; mm >>= adv;    // adv <= 21 < 64
                continue;
            }
            if (mm == 0) break;
            int z = __builtin_ctzll(mm);
            pos += z; mm >>= z;
            ts[nf++] = (unsigned short)(c * 64 + pos);
            dep = 21; ++pos; mm >>= 1;
        }
    }
    for (int i = 0; i < nf; ++i) {
        int t = ts[i];
        int a = argT[(b * 9 + (t >> 6)) * 64 + (t & 63)];
        out[(size_t)b * (NEURONS * TP) + (size_t)a * TP + t] = 1.0f;
    }
}

extern "C" void kernel_launch(void* const* d_in, const int* in_sizes, int n_in,
                              void* d_out, int out_size, void* d_ws, size_t ws_size,
                              hipStream_t stream) {
    const float* x      = (const float*)d_in[0];
    const int*   weight = (const int*)d_in[1];
    const int*   wk     = (const int*)d_in[2];

    char* ws = (char*)d_ws;
    uint2*              Apk     = (uint2*)(ws);                        // 3,211,264 B
    uint32_t*           xbT     = (uint32_t*)(ws + 3211264);           // 3,612,672 B
    unsigned long long* partial = (unsigned long long*)(ws + 6823936); //   270,336 B
    int*                argT    = (int*)(ws + 7094272);                //   147,456 B
    unsigned long long* fireM   = (unsigned long long*)(ws + 7241728); //     4,608 B
    uint4*              Bg      = (uint4*)(ws + 7246336);              // 211,746,816 B
    const size_t WS_SPLIT_NEED = 7246336ull + 211746816ull;            // ~219 MB

    float* out = (float*)d_out;

    hipMemsetAsync(out, 0, (size_t)out_size * 4, stream);
    hipMemsetAsync(partial, 0, NCOL * 8, stream);
    k_apack<<<1568, 256, 0, stream>>>(weight, Apk);
    k_xbitsT<<<3136, 256, 0, stream>>>(x, xbT);
    if (ws_size >= WS_SPLIT_NEED) {
        k_bbuild<<<dim3(528, 2), 256, 0, stream>>>(xbT, wk, Bg);
        k_gemm2<<<528, 256, 0, stream>>>((const i32x4*)Apk, (const i32x4*)Bg, partial);
    } else {
        k_gemm_fused<<<dim3(4, NCOL / 128), 256, 0, stream>>>((const i32x4*)Apk, xbT, wk, partial);
    }
    k_fire<<<144, 256, 0, stream>>>(partial, argT, fireM);
    k_scan<<<1, 64, 0, stream>>>(fireM, argT, out);
}